// Round 1
// 2978.764 us; speedup vs baseline: 2.8563x; 2.8563x over previous
//
#include <hip/hip_runtime.h>
#include <hip/hip_bf16.h>

// StaticCrossAttention on MI355X (gfx950). Inputs/output fp32 (per reference);
// internal compute bf16 MFMA with fp32 accumulation; intermediates bf16 in ws.
//   q = rmsnorm(hs @ Wq + bq, gq); kv = ctx @ Wkv + bkv; k = rmsnorm(kv[:DIM], gk)
//   out = softmax(q kT * sc) v ;  y = out @ Wo + bo
// Round 3: MFMA attention. attention_k was 81% of runtime with MfmaUtil=0
// (scalar VALU). Rewritten: 1 wave per 16 q-rows, full L=512 scores in regs,
// QK^T + PV via mfma_f32_16x16x32_bf16 with direct-global fragment loads
// (K is natively B-frag-shaped; V pre-transposed by vtrans_k so PV B-frags
// are contiguous). P relayout via tiny per-wave LDS buffer (stride 40).
// Fragment conventions (verified by the working GEMM below):
//   A-frag: lane holds A[l&15][(l>>4)*8+e]  (contiguous 8 along K)
//   B-frag: lane holds B[(l>>4)*8+e][l&15]
//   D:      col=l&15, row=(l>>4)*4+reg

typedef __hip_bfloat16 bf16;
typedef unsigned short u16;
typedef __bf16 bf16x8 __attribute__((ext_vector_type(8)));
typedef float f32x4 __attribute__((ext_vector_type(4)));
typedef u16 u16x8 __attribute__((ext_vector_type(8)));

#define DIMC 5120
#define H_ 40
#define HD_ 128
#define B_ 2
#define S_ 4096
#define L_ 512
#define EPSF 1e-6f
#define SCALEF 0.08838834764831845f  // 128^-0.5
#define SC2F (0.08838834764831845f * 1.4426950408889634f)  // SCALE * log2(e)

__device__ __forceinline__ float b2f(u16 x) {
    return __uint_as_float(((unsigned)x) << 16);
}
__device__ __forceinline__ u16 f2b(float f) {
    bf16 t = __float2bfloat16(f);
    return *reinterpret_cast<u16*>(&t);
}

// ---------------------------------------------------------------------------
// C[M,N] = A[M,K] @ W[K,N] + bias[N].  A: fp32 or bf16 (TA), W/bias: fp32,
// C: bf16 or fp32 (TC). fp32->bf16 conversion inline during LDS staging.
// Block 256 = 4 waves (2x2), wave does 64x64 via 4x4 MFMA 16x16x32 tiles.
// LDS octet-swizzled: octet' = octet ^ ((row>>1)&3) -> <=2-way bank alias (free).
template <typename TA, typename TC>
__global__ __launch_bounds__(256)
void gemm_bias_k(const TA* __restrict__ A, const float* __restrict__ W,
                 const float* __restrict__ bias, TC* __restrict__ C,
                 int N, int K) {
    __shared__ __align__(16) u16 sA[128 * 32];
    __shared__ __align__(16) u16 sB[128 * 32];
    const int tid = threadIdx.x;
    const int lane = tid & 63;
    const int wv = tid >> 6;
    const int wr = wv >> 1, wc = wv & 1;
    const int m0 = blockIdx.y * 128;
    const int n0 = blockIdx.x * 128;
    const int l16 = lane & 15;
    const int koct = lane >> 4;  // 0..3

    f32x4 acc[4][4] = {};

    for (int kt = 0; kt < K; kt += 32) {
        // --- stage A tile: 128 rows x 32 k, 512 octets, 2 per thread
#pragma unroll
        for (int it = 0; it < 2; ++it) {
            int flat = tid + it * 256;
            int row = flat >> 2;
            int oc = flat & 3;
            u16x8 v;
            if constexpr (sizeof(TA) == 2) {
                v = *reinterpret_cast<const u16x8*>(
                    (const u16*)A + (size_t)(m0 + row) * K + kt + oc * 8);
            } else {
                const float* p = (const float*)A + (size_t)(m0 + row) * K + kt + oc * 8;
                f32x4 a0 = *reinterpret_cast<const f32x4*>(p);
                f32x4 a1 = *reinterpret_cast<const f32x4*>(p + 4);
#pragma unroll
                for (int e = 0; e < 4; ++e) {
                    v[e] = f2b(a0[e]);
                    v[e + 4] = f2b(a1[e]);
                }
            }
            int soc = oc ^ ((row >> 1) & 3);
            *reinterpret_cast<u16x8*>(&sA[row * 32 + soc * 8]) = v;
        }
        // --- stage B tile transposed: sB[n][k]; coalesced 4B reads along n
        {
            int n = tid & 127;
            int kb = tid >> 7;  // 0..1
#pragma unroll
            for (int it = 0; it < 2; ++it) {
                int oc = kb + it * 2;  // 0..3
                u16x8 v;
#pragma unroll
                for (int j = 0; j < 8; ++j)
                    v[j] = f2b(W[(size_t)(kt + oc * 8 + j) * N + n0 + n]);
                int soc = oc ^ ((n >> 1) & 3);
                *reinterpret_cast<u16x8*>(&sB[n * 32 + soc * 8]) = v;
            }
        }
        __syncthreads();

        bf16x8 af[4], bfr[4];
#pragma unroll
        for (int i = 0; i < 4; ++i) {
            int m = wr * 64 + i * 16 + l16;
            int soc = koct ^ ((m >> 1) & 3);
            af[i] = *reinterpret_cast<const bf16x8*>(&sA[m * 32 + soc * 8]);
        }
#pragma unroll
        for (int j = 0; j < 4; ++j) {
            int n = wc * 64 + j * 16 + l16;
            int soc = koct ^ ((n >> 1) & 3);
            bfr[j] = *reinterpret_cast<const bf16x8*>(&sB[n * 32 + soc * 8]);
        }
#pragma unroll
        for (int i = 0; i < 4; ++i)
#pragma unroll
            for (int j = 0; j < 4; ++j)
                acc[i][j] = __builtin_amdgcn_mfma_f32_16x16x32_bf16(
                    af[i], bfr[j], acc[i][j], 0, 0, 0);
        __syncthreads();
    }

    // epilogue: C/D layout col=lane&15, row=(lane>>4)*4+reg (m89-verified)
#pragma unroll
    for (int i = 0; i < 4; ++i) {
        int mbase = m0 + wr * 64 + i * 16 + (lane >> 4) * 4;
#pragma unroll
        for (int j = 0; j < 4; ++j) {
            int n = n0 + wc * 64 + j * 16 + l16;
            float bv = bias[n];
#pragma unroll
            for (int r = 0; r < 4; ++r) {
                float val = acc[i][j][r] + bv;
                if constexpr (sizeof(TC) == 2)
                    C[(size_t)(mbase + r) * N + n] = __float2bfloat16(val);
                else
                    C[(size_t)(mbase + r) * N + n] = val;
            }
        }
    }
}

// ---------------------------------------------------------------------------
// In-place RMSNorm over width 5120 (bf16 row, fp32 gain), one 256-thr block/row.
__global__ __launch_bounds__(256)
void rmsnorm_k(bf16* __restrict__ x, const float* __restrict__ g, int stride) {
    __shared__ float red[4];
    u16* row = (u16*)x + (size_t)blockIdx.x * stride;
    const int tid = threadIdx.x;
    float ss = 0.f;
    for (int oc = tid; oc < 640; oc += 256) {
        u16x8 v = *reinterpret_cast<const u16x8*>(row + oc * 8);
#pragma unroll
        for (int e = 0; e < 8; ++e) {
            float f = b2f(v[e]);
            ss += f * f;
        }
    }
#pragma unroll
    for (int off = 32; off > 0; off >>= 1) ss += __shfl_down(ss, off);
    if ((tid & 63) == 0) red[tid >> 6] = ss;
    __syncthreads();
    float rs = rsqrtf((red[0] + red[1] + red[2] + red[3]) * (1.0f / 5120.0f) + EPSF);
    for (int oc = tid; oc < 640; oc += 256) {
        u16x8 v = *reinterpret_cast<const u16x8*>(row + oc * 8);
        f32x4 g0 = *reinterpret_cast<const f32x4*>(g + oc * 8);
        f32x4 g1 = *reinterpret_cast<const f32x4*>(g + oc * 8 + 4);
        u16x8 o;
#pragma unroll
        for (int e = 0; e < 4; ++e) {
            o[e] = f2b(b2f(v[e]) * rs * g0[e]);
            o[e + 4] = f2b(b2f(v[e + 4]) * rs * g1[e]);
        }
        *reinterpret_cast<u16x8*>(row + oc * 8) = o;
    }
}

// ---------------------------------------------------------------------------
// V transpose: kvbuf V-part [b][l][h*128+d] -> vt[(b*H+h)*128 + d][l]
// so PV B-frags (8 contiguous keys at fixed d) are u16x8 global loads.
// Block: one (b,h), 64 l-rows x 128 d. LDS tile padded to stride 130 u16.
__global__ __launch_bounds__(256)
void vtrans_k(const bf16* __restrict__ KV, bf16* __restrict__ VT) {
    __shared__ u16 sT[64][130];
    const int tid = threadIdx.x;
    const int bh = blockIdx.x;  // 0..79
    const int b = bh / H_;
    const int h = bh - b * H_;
    const int l0 = blockIdx.y * 64;
    const u16* src = (const u16*)KV + (size_t)b * L_ * (2 * DIMC) + DIMC + h * HD_;
#pragma unroll
    for (int it = 0; it < 4; ++it) {
        int flat = it * 256 + tid;  // 0..1023
        int l = flat >> 4;          // 0..63
        int dq = flat & 15;         // 16 x u16x8 per 128-wide row
        u16x8 v = *reinterpret_cast<const u16x8*>(
            src + (size_t)(l0 + l) * (2 * DIMC) + dq * 8);
#pragma unroll
        for (int e = 0; e < 8; ++e) sT[l][dq * 8 + e] = v[e];
    }
    __syncthreads();
    u16* dst = (u16*)VT + (size_t)bh * HD_ * L_ + l0;
#pragma unroll
    for (int it = 0; it < 4; ++it) {
        int flat = it * 256 + tid;  // 0..1023
        int d = flat >> 3;          // 0..127
        int ls = (flat & 7) * 8;    // 0..56
        u16x8 v;
#pragma unroll
        for (int e = 0; e < 8; ++e) v[e] = sT[ls + e][d];
        *reinterpret_cast<u16x8*>(dst + (size_t)d * L_ + ls) = v;
    }
}

// ---------------------------------------------------------------------------
// MFMA attention. One wave per 16 q-rows of one (b,h); full L=512 scores in
// registers (32 x f32x4); full softmax (no online rescale needed); PV with
// P routed through a per-wave LDS buffer (stride 40 u16: conflict-light) and
// V read from the pre-transposed VT.
__global__ __launch_bounds__(256)
void attention_k(const bf16* __restrict__ Q, const bf16* __restrict__ KV,
                 const bf16* __restrict__ VT, bf16* __restrict__ O) {
    __shared__ __align__(16) u16 sP[4][16 * 40];
    const int tid = threadIdx.x;
    const int wv = tid >> 6, lane = tid & 63;
    const int l16 = lane & 15, g = lane >> 4;
    const int tile = blockIdx.x * 4 + wv;  // 0..20479; 256 tiles per (b,h)
    const int bh = tile >> 8;
    const int st = tile & 255;
    const int b = bh / H_;
    const int h = bh - b * H_;
    const int q0 = st * 16;
    const u16* qbase = (const u16*)Q + ((size_t)b * S_ + q0) * DIMC + h * HD_;
    const u16* kbase = (const u16*)KV + (size_t)b * L_ * (2 * DIMC) + h * HD_;
    const u16* vtb = (const u16*)VT + (size_t)bh * HD_ * L_;

    // Q A-frags: lane holds Q[q0 + l16][kc*32 + g*8 + e]
    bf16x8 aq[4];
    {
        const u16* qr = qbase + (size_t)l16 * DIMC + g * 8;
#pragma unroll
        for (int kc = 0; kc < 4; ++kc)
            aq[kc] = *reinterpret_cast<const bf16x8*>(qr + kc * 32);
    }

    // QK^T: scores S[16][512]; s[nt] holds cols nt*16+l16, rows g*4+r.
    // K row [key][d] is natively B-frag-shaped: contiguous u16x8 along d.
    f32x4 s[32];
#pragma unroll
    for (int nt = 0; nt < 32; ++nt) s[nt] = f32x4{0.f, 0.f, 0.f, 0.f};
#pragma unroll
    for (int nt = 0; nt < 32; ++nt) {
        const u16* kr = kbase + (size_t)(nt * 16 + l16) * (2 * DIMC) + g * 8;
        bf16x8 b0 = *reinterpret_cast<const bf16x8*>(kr);
        bf16x8 b1 = *reinterpret_cast<const bf16x8*>(kr + 32);
        bf16x8 b2 = *reinterpret_cast<const bf16x8*>(kr + 64);
        bf16x8 b3 = *reinterpret_cast<const bf16x8*>(kr + 96);
        s[nt] = __builtin_amdgcn_mfma_f32_16x16x32_bf16(aq[0], b0, s[nt], 0, 0, 0);
        s[nt] = __builtin_amdgcn_mfma_f32_16x16x32_bf16(aq[1], b1, s[nt], 0, 0, 0);
        s[nt] = __builtin_amdgcn_mfma_f32_16x16x32_bf16(aq[2], b2, s[nt], 0, 0, 0);
        s[nt] = __builtin_amdgcn_mfma_f32_16x16x32_bf16(aq[3], b3, s[nt], 0, 0, 0);
    }

    // softmax: row q=g*4+r lives in the 16 lanes sharing g (l16 = col&15).
    // Reduce: 32 in-lane cols, then shfl_xor 1/2/4/8 within the 16-lane group.
    // SCALE folded into exp2: p = exp2((s - max)*SCALE*log2e).
    float inv[4];
#pragma unroll
    for (int r = 0; r < 4; ++r) {
        float m = s[0][r];
#pragma unroll
        for (int nt = 1; nt < 32; ++nt) m = fmaxf(m, s[nt][r]);
#pragma unroll
        for (int off = 1; off < 16; off <<= 1) m = fmaxf(m, __shfl_xor(m, off));
        float sum = 0.f;
#pragma unroll
        for (int nt = 0; nt < 32; ++nt) {
            float p = exp2f((s[nt][r] - m) * SC2F);
            s[nt][r] = p;  // reuse score storage for P
            sum += p;
        }
#pragma unroll
        for (int off = 1; off < 16; off <<= 1) sum += __shfl_xor(sum, off);
        inv[r] = 1.f / sum;
    }

    // PV: per 32-key chunk c, relayout P (D-layout -> A-frag) through
    // wave-private LDS (in-order DS pipe; no barrier needed), then 8 MFMAs
    // with B-frags from VT (contiguous u16x8: 8 keys at fixed d).
    f32x4 o[8];
#pragma unroll
    for (int dt = 0; dt < 8; ++dt) o[dt] = f32x4{0.f, 0.f, 0.f, 0.f};
    u16* myP = &sP[wv][0];
#pragma unroll
    for (int c = 0; c < 16; ++c) {
#pragma unroll
        for (int t = 0; t < 2; ++t) {
            int nt = c * 2 + t;
#pragma unroll
            for (int r = 0; r < 4; ++r)
                myP[(g * 4 + r) * 40 + t * 16 + l16] = f2b(s[nt][r]);
        }
        bf16x8 ap = *reinterpret_cast<const bf16x8*>(myP + l16 * 40 + g * 8);
#pragma unroll
        for (int dt = 0; dt < 8; ++dt) {
            const u16* vr = vtb + (size_t)(dt * 16 + l16) * L_ + c * 32 + g * 8;
            bf16x8 bv = *reinterpret_cast<const bf16x8*>(vr);
            o[dt] = __builtin_amdgcn_mfma_f32_16x16x32_bf16(ap, bv, o[dt], 0, 0, 0);
        }
    }

    // epilogue: O row = g*4+r, col = dt*16+l16; normalize by 1/sum here.
    u16* ob = (u16*)O + ((size_t)b * S_ + q0) * DIMC + h * HD_;
#pragma unroll
    for (int r = 0; r < 4; ++r) {
        float iv = inv[r];
        size_t rowoff = (size_t)(g * 4 + r) * DIMC;
#pragma unroll
        for (int dt = 0; dt < 8; ++dt)
            ob[rowoff + dt * 16 + l16] = f2b(o[dt][r] * iv);
    }
}

// ---------------------------------------------------------------------------
extern "C" void kernel_launch(void* const* d_in, const int* in_sizes, int n_in,
                              void* d_out, int out_size, void* d_ws, size_t ws_size,
                              hipStream_t stream) {
    const float* hs  = (const float*)d_in[0];
    const float* ctx = (const float*)d_in[1];
    const float* Wq  = (const float*)d_in[2];
    const float* bq  = (const float*)d_in[3];
    const float* Wkv = (const float*)d_in[4];
    const float* bkv = (const float*)d_in[5];
    const float* gq  = (const float*)d_in[6];
    const float* gk  = (const float*)d_in[7];
    const float* Wo  = (const float*)d_in[8];
    const float* bo  = (const float*)d_in[9];
    float* out = (float*)d_out;

    char* ws = (char*)d_ws;
    const size_t QBYTES  = (size_t)8192 * 5120 * 2;   // 83,886,080
    const size_t KVBYTES = (size_t)1024 * 10240 * 2;  // 20,971,520
    const size_t AOBYTES = (size_t)8192 * 5120 * 2;   // 83,886,080
    bf16* qbuf  = (bf16*)ws;
    bf16* kvbuf = (bf16*)(ws + QBYTES);
    bf16* aobuf = (bf16*)(ws + QBYTES + KVBYTES);
    bf16* vtbuf = (bf16*)(ws + QBYTES + KVBYTES + AOBYTES);  // 10,485,760 B

    dim3 blk(256);
    // q = hs @ Wq + bq   [8192,5120] (bf16)
    gemm_bias_k<float, bf16><<<dim3(40, 64), blk, 0, stream>>>(hs, Wq, bq, qbuf, 5120, 5120);
    // rmsnorm(q) * gq, in place
    rmsnorm_k<<<dim3(8192), blk, 0, stream>>>(qbuf, gq, 5120);
    // kv = ctx @ Wkv + bkv   [1024,10240] (bf16)
    gemm_bias_k<float, bf16><<<dim3(80, 8), blk, 0, stream>>>(ctx, Wkv, bkv, kvbuf, 10240, 5120);
    // rmsnorm(kv[:, :5120]) * gk, in place (K half only)
    rmsnorm_k<<<dim3(1024), blk, 0, stream>>>(kvbuf, gk, 10240);
    // vt[(b*H+h)*128+d][l] = v  (PV B-frag layout)
    vtrans_k<<<dim3(80, 8), blk, 0, stream>>>(kvbuf, vtbuf);
    // attention -> aobuf [8192,5120] (bf16); 1 wave / 16 q-rows, 4 waves/block
    attention_k<<<dim3(5120), blk, 0, stream>>>(qbuf, kvbuf, vtbuf, aobuf);
    // out = aobuf @ Wo + bo  (fp32 out)
    gemm_bias_k<bf16, float><<<dim3(40, 64), blk, 0, stream>>>(aobuf, Wo, bo, out, 5120, 5120);
}